// Round 2
// baseline (239.434 us; speedup 1.0000x reference)
//
#include <hip/hip_runtime.h>

// TSAdaptivePatcher: x[64][64][8192] f32, mask[64][8192] i32
// PATCH=STRIDE=16 -> n_patches=512, non-overlapping => pure (c,p)-chunk transpose
// out = [ patches: 64*512*1024 f32 ][ padding_mask: 64*512 f32 ]
//
// v3: persistent pipelined blocks. grid=512 (exactly 2/CU), each block owns
// 64 consecutive patches = 8 tiles of (64c x 8p) = 8 x 32 KiB, double-buffered
// through 64 KiB LDS with counted vmcnt (never 0 in the loop) + raw s_barrier.
//  - Phase 1: global_load_lds (no VGPR round-trip). LDS dest linear
//    (HW requirement); XOR bank-swizzle applied to the per-lane GLOBAL source
//    chunk (involution), re-applied on the ds_read side (rule: both-sides).
//  - Phase 2: ds_read_b128 (uniform 8 lanes per 4-bank group = inherent min)
//    + 1 KiB-contiguous stores per wave-instr; 32 KiB contiguous per tile.
//  - vmcnt discipline: at tile t, ops newer than loads(t) = stores(t-1) [4]
//    + loads(t+1) [4] -> s_waitcnt vmcnt(8) (4 at pipeline ends). Loads for
//    t+2 issued after the tail barrier -> reads & writes overlap continuously.

typedef float f4 __attribute__((ext_vector_type(4)));

constexpr int Bb  = 64;
constexpr int Cc  = 64;
constexpr int Ss  = 8192;
constexpr int NP  = 512;     // 1 + (8192-16)/16
constexpr int PT  = 8;       // patches per tile (tile = 64c x 8p = 32 KiB)
constexpr int T   = 8;       // tiles per block (block owns 64 patches)
constexpr size_t PATCH_ELEMS = (size_t)Bb * NP * Cc * 16; // 33,554,432

__global__ __launch_bounds__(512) void ts_patcher_kernel(
    const float* __restrict__ x,
    const int*   __restrict__ mask,
    float*       __restrict__ out)
{
    __shared__ f4 lds[2 * Cc * 32];   // 2 buffers x 32 KiB = 65536 B

    const int t   = threadIdx.x;
    const int w   = t >> 6;            // wave 0..7
    const int l   = t & 63;            // lane
    const int blk = blockIdx.x;
    const int b   = blk >> 3;          // 8 blocks per batch
    const int P0  = (blk & 7) * (PT * T);  // first of this block's 64 patches

    const float* xb = x + (size_t)b * Cc * Ss + (size_t)P0 * 16;

    f4* bufA = lds;
    f4* bufB = lds + Cc * 32;

    // Stage one tile (64 rows x 512 B) into buf: 4 global_load_lds per thread.
    // Wave w, instr i covers rows {16i+2w, 16i+2w+1}; lane l -> row c = +l>>5,
    // source chunk g = (l&31) ^ (c&7)  [XOR involution pre-applied on source,
    // LDS dest stays linear: buf[c*32 + (l&31)] <- rowdata[c][(l&31)^(c&7)]].
    auto STAGE = [&](int tile, f4* buf) {
#pragma unroll
        for (int i = 0; i < 4; ++i) {
            const int c = 16 * i + 2 * w + (l >> 5);
            const int g = (l & 31) ^ (c & 7);
            const float* src = xb + (size_t)tile * (PT * 16)
                                  + (size_t)c * Ss + (size_t)g * 4;
            __builtin_amdgcn_global_load_lds(
                (const __attribute__((address_space(1))) void*)src,
                (__attribute__((address_space(3))) void*)&buf[(16 * i + 2 * w) * 32],
                16, 0, 0);
        }
    };

    STAGE(0, bufA);
    STAGE(1, bufB);

    f4* ob = (f4*)(out + (size_t)(b * NP + P0) * (Cc * 16));

#pragma unroll
    for (int tile = 0; tile < T; ++tile) {
        // wait for loads(tile): newer ops = stores(tile-1)[4] + loads(tile+1)[4]
        if (tile == 0 || tile == T - 1) {
            asm volatile("s_waitcnt vmcnt(4)" ::: "memory");
        } else {
            asm volatile("s_waitcnt vmcnt(8)" ::: "memory");
        }
        __builtin_amdgcn_s_barrier();   // all waves' loads(tile) landed in LDS

        f4* buf = (tile & 1) ? bufB : bufA;
        f4* ot  = ob + (size_t)tile * (PT * 256);   // 32 KiB contiguous tile-out
#pragma unroll
        for (int j = 0; j < 4; ++j) {
            const int o  = (j * 8 + w) * 64 + l;    // float4 idx in tile-out
            const int p  = o >> 8;                  // patch-local 0..7 (const/instr)
            const int r  = o & 255;
            const int c  = r >> 2;
            const int jj = r & 3;
            ot[o] = buf[c * 32 + ((4 * p + jj) ^ (c & 7))];
        }
        __builtin_amdgcn_s_barrier();   // all waves consumed buf (ds_reads done)
        if (tile + 2 < T) STAGE(tile + 2, buf);   // refill same parity buffer
    }

    // ---- Fused padding mask: threads 0..63, one of this block's patches ----
    if (t < PT * T) {
        const int p = P0 + t;
        const int4* m = (const int4*)(mask + (size_t)b * Ss + (size_t)p * 16);
        int4 a = m[0], d = m[1], e = m[2], f = m[3];
        int s = a.x + a.y + a.z + a.w
              + d.x + d.y + d.z + d.w
              + e.x + e.y + e.z + e.w
              + f.x + f.y + f.z + f.w;
        // mean >= 0.5  <=>  sum >= 8  (mask values in {0,1})
        out[PATCH_ELEMS + (size_t)b * NP + p] = (s >= 8) ? 1.0f : 0.0f;
    }
}

extern "C" void kernel_launch(void* const* d_in, const int* in_sizes, int n_in,
                              void* d_out, int out_size, void* d_ws, size_t ws_size,
                              hipStream_t stream) {
    const float* x    = (const float*)d_in[0];
    const int*   mask = (const int*)d_in[1];
    float*       out  = (float*)d_out;

    const int blocks = Bb * (NP / (PT * T));   // 64 * 8 = 512, exactly 2/CU
    ts_patcher_kernel<<<blocks, 512, 0, stream>>>(x, mask, out);
}